// Round 1
// baseline (1157.058 us; speedup 1.0000x reference)
//
#include <hip/hip_runtime.h>

// LoHA: out = x @ (W + (a0@b0/16) * (a1@b1/16)) + bias
// R3: (1) gemm rebuilt as 256x256 tile, BK=32, 8 waves (512 thr), 4-deep LDS
//     pipeline (128 KiB), ONE s_barrier + counted s_waitcnt vmcnt(8) per
//     K-tile (no vmcnt(0) drain in main loop), setprio(1) around MFMA
//     clusters, XCD-chunked block swizzle. Same proven XOR staging swizzle.
//     (2) prep split: cvt_x standalone (no LDS -> full occupancy);
//     prep_bt with a-rows in registers + broadcast float4 b-reads
//     (~8 LDS instr/output vs 64).
// Workspace: xb (bf16, 134217728 B) @ 0; Bt (bf16, 33554432 B) @ 134217728.

#define D_IN   4096
#define D_OUT  4096
#define RANKR  16
#define MROWS  16384
#define NTK    128   // K tiles of BK=32

typedef __attribute__((ext_vector_type(8))) short short8;
typedef __attribute__((ext_vector_type(4))) float floatx4;

__device__ __forceinline__ unsigned short f2bf(float f) {
    union { float f; unsigned u; } c; c.f = f;
    unsigned r = c.u + 0x7fffu + ((c.u >> 16) & 1u);   // round-to-nearest-even
    return (unsigned short)(r >> 16);
}

__device__ __forceinline__ void glds16(const void* g, void* l) {
    __builtin_amdgcn_global_load_lds(
        (const __attribute__((address_space(1))) void*)g,
        (__attribute__((address_space(3))) void*)l, 16, 0, 0);
}

// ---------------------------------------------------------------------------
// cvt_x: x fp32 -> bf16, 8 elem/thread, no LDS (full occupancy streaming)
// ---------------------------------------------------------------------------
__global__ __launch_bounds__(256) void cvt_x(const float* __restrict__ x,
                                             unsigned short* __restrict__ xb) {
    size_t i = ((size_t)blockIdx.x * 256 + threadIdx.x) * 8;
    const float4* p = (const float4*)(x + i);
    float4 v0 = p[0], v1 = p[1];
    union { unsigned short u[8]; uint4 q; } o;
    o.u[0] = f2bf(v0.x); o.u[1] = f2bf(v0.y);
    o.u[2] = f2bf(v0.z); o.u[3] = f2bf(v0.w);
    o.u[4] = f2bf(v1.x); o.u[5] = f2bf(v1.y);
    o.u[6] = f2bf(v1.z); o.u[7] = f2bf(v1.w);
    *(uint4*)(xb + i) = o.q;
}

// ---------------------------------------------------------------------------
// prep_bt: Bt[n][k] = bf16(W[k][n] + s^2*(a0@b0)[k][n]*(a1@b1)[k][n])
// 64x64 tiles. kk = tid&63 is thread-invariant -> a-rows live in registers;
// b-factors staged transposed [nn][r] (pad 20 for 16B-aligned float4) and
// read as wave-uniform broadcast float4 (conflict-free).
// ---------------------------------------------------------------------------
__global__ __launch_bounds__(256) void prep_bt(
    const float* __restrict__ W,  const float* __restrict__ a0,
    const float* __restrict__ b0, const float* __restrict__ a1,
    const float* __restrict__ b1, unsigned short* __restrict__ Bt) {
    __shared__ float Wt[64][65];
    __shared__ float b0t[64][20], b1t[64][20];   // [nn][r], stride 20
    const int tid = threadIdx.x;
    const int k0 = (blockIdx.x & 63) * 64, n0 = (blockIdx.x >> 6) * 64;

    #pragma unroll
    for (int i = 0; i < 16; ++i) {
        int e = i * 256 + tid;
        int kk = e >> 6, nn = e & 63;
        Wt[kk][nn] = W[(size_t)(k0 + kk) * D_OUT + n0 + nn];
    }
    #pragma unroll
    for (int i = 0; i < 4; ++i) {
        int e = i * 256 + tid;
        int r = e >> 6, nn = e & 63;
        b0t[nn][r] = b0[(size_t)r * D_OUT + n0 + nn];
        b1t[nn][r] = b1[(size_t)r * D_OUT + n0 + nn];
    }
    const int kk = tid & 63;
    float4 A0[4], A1[4];
    #pragma unroll
    for (int c = 0; c < 4; ++c) {
        A0[c] = *(const float4*)(a0 + (size_t)(k0 + kk) * RANKR + c * 4);
        A1[c] = *(const float4*)(a1 + (size_t)(k0 + kk) * RANKR + c * 4);
    }
    __syncthreads();

    const float s2 = 1.0f / 256.0f;   // (ALPHA/RANK)^2
    #pragma unroll
    for (int i = 0; i < 16; ++i) {
        int nn = i * 4 + (tid >> 6);          // wave-uniform -> broadcast reads
        float d0 = 0.f, d1 = 0.f;
        #pragma unroll
        for (int c = 0; c < 4; ++c) {
            float4 bv0 = *(const float4*)&b0t[nn][c * 4];
            float4 bv1 = *(const float4*)&b1t[nn][c * 4];
            d0 += A0[c].x * bv0.x + A0[c].y * bv0.y + A0[c].z * bv0.z + A0[c].w * bv0.w;
            d1 += A1[c].x * bv1.x + A1[c].y * bv1.y + A1[c].z * bv1.z + A1[c].w * bv1.w;
        }
        float v = Wt[kk][nn] + s2 * d0 * d1;
        Bt[(size_t)(n0 + nn) * D_IN + k0 + kk] = f2bf(v);
    }
}

// ---------------------------------------------------------------------------
// gemm: C[m][n] = sum_k A[m][k]*Bt[n][k] + bias[n]   (bf16 MFMA, fp32 acc)
// 256x256 block tile, BK=32, 8 waves 2(M)x4(N), each wave 128x64 out.
// 4-deep LDS pipeline: stage of tile t+3 issued inside tile t; one barrier +
// vmcnt(8) per tile (tile t+1's 4 loads are the oldest 4 of 12 in flight).
// LDS tiles XOR-swizzled (chunk ^= (row>>2)&3) via per-lane global address.
// ---------------------------------------------------------------------------
#define STAGE_A(tt) do {                                                      \
    const int kt_ = (tt) * 32;                                                \
    unsigned short* const dst_ = &As[(tt) & 3][0];                            \
    _Pragma("unroll")                                                         \
    for (int r_ = 0; r_ < 2; ++r_) {                                          \
      const int e_ = r_ * 512 + tid;                                          \
      const int row_ = e_ >> 2;                                               \
      const int cc_ = ((e_ & 3) ^ ((row_ >> 2) & 3)) * 8;                     \
      glds16(Ag + (size_t)row_ * D_IN + kt_ + cc_,                            \
             (char*)dst_ + r_ * 8192 + wave * 1024);                          \
    }                                                                         \
  } while (0)

#define STAGE_B(tt) do {                                                      \
    const int kt_ = (tt) * 32;                                                \
    unsigned short* const dst_ = &Bs[(tt) & 3][0];                            \
    _Pragma("unroll")                                                         \
    for (int r_ = 0; r_ < 2; ++r_) {                                          \
      const int e_ = r_ * 512 + tid;                                          \
      const int row_ = e_ >> 2;                                               \
      const int cc_ = ((e_ & 3) ^ ((row_ >> 2) & 3)) * 8;                     \
      glds16(Bg + (size_t)row_ * D_IN + kt_ + cc_,                            \
             (char*)dst_ + r_ * 8192 + wave * 1024);                          \
    }                                                                         \
  } while (0)

#define TILE(tt, DS) do {                                                     \
    const unsigned short* const as_ = &As[(tt) & 3][0];                       \
    const unsigned short* const bs_ = &Bs[(tt) & 3][0];                       \
    if (DS) STAGE_A((tt) + 3);                                                \
    short8 bfr[4], afr[4];                                                    \
    _Pragma("unroll")                                                         \
    for (int nt_ = 0; nt_ < 4; ++nt_)                                         \
      bfr[nt_] = *(const short8*)(bs_ + (wn * 64 + nt_ * 16 + l16) * 32 + rc8); \
    _Pragma("unroll")                                                         \
    for (int mt_ = 0; mt_ < 4; ++mt_)                                         \
      afr[mt_] = *(const short8*)(as_ + (wm * 128 + mt_ * 16 + l16) * 32 + rc8); \
    __builtin_amdgcn_s_setprio(1);                                            \
    _Pragma("unroll")                                                         \
    for (int mt_ = 0; mt_ < 4; ++mt_)                                         \
      _Pragma("unroll")                                                       \
      for (int nt_ = 0; nt_ < 4; ++nt_)                                       \
        acc[mt_][nt_] = __builtin_amdgcn_mfma_f32_16x16x32_bf16(              \
            afr[mt_], bfr[nt_], acc[mt_][nt_], 0, 0, 0);                      \
    __builtin_amdgcn_s_setprio(0);                                            \
    if (DS) STAGE_B((tt) + 3);                                                \
    _Pragma("unroll")                                                         \
    for (int mt_ = 0; mt_ < 4; ++mt_)                                         \
      afr[mt_] = *(const short8*)(as_ + (wm * 128 + 64 + mt_ * 16 + l16) * 32 + rc8); \
    __builtin_amdgcn_s_setprio(1);                                            \
    _Pragma("unroll")                                                         \
    for (int mt_ = 0; mt_ < 4; ++mt_)                                         \
      _Pragma("unroll")                                                       \
      for (int nt_ = 0; nt_ < 4; ++nt_)                                       \
        acc[4 + mt_][nt_] = __builtin_amdgcn_mfma_f32_16x16x32_bf16(          \
            afr[mt_], bfr[nt_], acc[4 + mt_][nt_], 0, 0, 0);                  \
    __builtin_amdgcn_s_setprio(0);                                            \
  } while (0)

#define TILE_SYNC(N) do {                                                     \
    asm volatile("s_waitcnt vmcnt(" #N ")" ::: "memory");                     \
    __builtin_amdgcn_s_barrier();                                             \
    asm volatile("" ::: "memory");                                            \
  } while (0)

__global__ __launch_bounds__(512, 2) void gemm_bt(
    const unsigned short* __restrict__ A,   // [MROWS][D_IN] bf16
    const unsigned short* __restrict__ B,   // [D_OUT][D_IN] bf16 (transposed)
    const float* __restrict__ bias,
    float* __restrict__ C) {
    __shared__ __align__(16) unsigned short As[4][256 * 32];   // 64 KiB
    __shared__ __align__(16) unsigned short Bs[4][256 * 32];   // 64 KiB

    const int tid  = threadIdx.x;
    const int wave = tid >> 6, lane = tid & 63;
    const int quad = lane >> 4, l16 = lane & 15;
    const int rc8  = (quad ^ (l16 >> 2)) * 8;      // swizzled read chunk

    // XCD-chunked swizzle: each XCD gets 8 consecutive m-panels (1024%8==0)
    const int bid = blockIdx.y * 16 + blockIdx.x;
    const int swz = (bid & 7) * 128 + (bid >> 3);
    const int m0 = (swz >> 4) * 256, n0 = (swz & 15) * 256;
    const int wm = wave >> 2, wn = wave & 3;       // 2x4 wave grid

    const unsigned short* Ag = A + (size_t)m0 * D_IN;
    const unsigned short* Bg = B + (size_t)n0 * D_IN;

    floatx4 acc[8][4] = {};

    // prologue: stage tiles 0,1,2 (12 loads); oldest 4 (= tile 0) must land
    STAGE_A(0); STAGE_B(0);
    STAGE_A(1); STAGE_B(1);
    STAGE_A(2); STAGE_B(2);
    TILE_SYNC(8);

    for (int t = 0; t < NTK - 3; ++t) {
        TILE(t, 1);
        TILE_SYNC(8);          // retires exactly tile t+1's 4 loads
    }
    TILE(NTK - 3, 0); TILE_SYNC(4);
    TILE(NTK - 2, 0); TILE_SYNC(0);
    TILE(NTK - 1, 0);

    // epilogue: C/D layout col=lane&15, row=quad*4+reg; fuse bias; NT stores
    #pragma unroll
    for (int nt = 0; nt < 4; ++nt) {
        int col = n0 + wn * 64 + nt * 16 + l16;
        float bv = bias[col];
        #pragma unroll
        for (int mt = 0; mt < 8; ++mt) {
            int r0 = m0 + wm * 128 + mt * 16 + quad * 4;
            #pragma unroll
            for (int r = 0; r < 4; ++r) {
                float v = acc[mt][nt][r] + bv;
                __builtin_nontemporal_store(v, &C[(size_t)(r0 + r) * D_OUT + col]);
            }
        }
    }
}

extern "C" void kernel_launch(void* const* d_in, const int* in_sizes, int n_in,
                              void* d_out, int out_size, void* d_ws, size_t ws_size,
                              hipStream_t stream) {
    const float* x    = (const float*)d_in[0];
    const float* W    = (const float*)d_in[1];
    const float* bias = (const float*)d_in[2];
    const float* a0   = (const float*)d_in[3];
    const float* b0   = (const float*)d_in[4];
    const float* a1   = (const float*)d_in[5];
    const float* b1   = (const float*)d_in[6];
    float* out = (float*)d_out;

    unsigned short* xb = (unsigned short*)d_ws;                                      // 128 MB
    unsigned short* Bt = (unsigned short*)((char*)d_ws + (size_t)MROWS * D_IN * 2);  // 32 MB

    cvt_x<<<(MROWS * (size_t)D_IN) / 2048, 256, 0, stream>>>(x, xb);
    prep_bt<<<4096, 256, 0, stream>>>(W, a0, b0, a1, b1, Bt);
    gemm_bt<<<dim3(D_OUT / 256, MROWS / 256), 512, 0, stream>>>(xb, Bt, bias, out);
}

// Round 3
// 1002.794 us; speedup vs baseline: 1.1538x; 1.1538x over previous
//
#include <hip/hip_runtime.h>

// LoHA: out = x @ (W + (a0@b0/16) * (a1@b1/16)) + bias
// R5: R4's 8-phase schedule with the K-tile count FIXED (R4 ran 128 tiles of
//     BK=64 = 8192 K-elements against D_IN=4096 -> accumulated garbage).
//     Structure: 256x256 tile, BK=64 split into two K-planes (256x32),
//     4 phases per K-tile, each {ds_read subtile; stage 1 half-plane of t+1;
//     [vmcnt(4) at P1/P3]; barrier; lgkm0; setprio+16 MFMA; barrier}.
//     Counted vmcnt never reaches 0 in the main loop. LDS chunk swizzle key
//     (row>>1)&3 -> every 8-lane b128 issue group covers all 8 bank-groups.
// Workspace: xb (bf16, 134217728 B) @ 0; Bt (bf16, 33554432 B) @ 134217728.

#define D_IN   4096
#define D_OUT  4096
#define RANKR  16
#define MROWS  16384
#define NTILES 64    // K tiles of BK=64  (64*64 = 4096 = D_IN)

typedef __attribute__((ext_vector_type(8))) short short8;
typedef __attribute__((ext_vector_type(4))) float floatx4;

__device__ __forceinline__ unsigned short f2bf(float f) {
    union { float f; unsigned u; } c; c.f = f;
    unsigned r = c.u + 0x7fffu + ((c.u >> 16) & 1u);   // round-to-nearest-even
    return (unsigned short)(r >> 16);
}

__device__ __forceinline__ void glds16(const void* g, void* l) {
    __builtin_amdgcn_global_load_lds(
        (const __attribute__((address_space(1))) void*)g,
        (__attribute__((address_space(3))) void*)l, 16, 0, 0);
}

// ---------------------------------------------------------------------------
// cvt_x: x fp32 -> bf16, 8 elem/thread, no LDS (full occupancy streaming)
// ---------------------------------------------------------------------------
__global__ __launch_bounds__(256) void cvt_x(const float* __restrict__ x,
                                             unsigned short* __restrict__ xb) {
    size_t i = ((size_t)blockIdx.x * 256 + threadIdx.x) * 8;
    const float4* p = (const float4*)(x + i);
    float4 v0 = p[0], v1 = p[1];
    union { unsigned short u[8]; uint4 q; } o;
    o.u[0] = f2bf(v0.x); o.u[1] = f2bf(v0.y);
    o.u[2] = f2bf(v0.z); o.u[3] = f2bf(v0.w);
    o.u[4] = f2bf(v1.x); o.u[5] = f2bf(v1.y);
    o.u[6] = f2bf(v1.z); o.u[7] = f2bf(v1.w);
    *(uint4*)(xb + i) = o.q;
}

// ---------------------------------------------------------------------------
// prep_bt: Bt[n][k] = bf16(W[k][n] + s^2*(a0@b0)[k][n]*(a1@b1)[k][n])
// ---------------------------------------------------------------------------
__global__ __launch_bounds__(256) void prep_bt(
    const float* __restrict__ W,  const float* __restrict__ a0,
    const float* __restrict__ b0, const float* __restrict__ a1,
    const float* __restrict__ b1, unsigned short* __restrict__ Bt) {
    __shared__ float Wt[64][65];
    __shared__ float b0t[64][20], b1t[64][20];   // [nn][r], stride 20
    const int tid = threadIdx.x;
    const int k0 = (blockIdx.x & 63) * 64, n0 = (blockIdx.x >> 6) * 64;

    #pragma unroll
    for (int i = 0; i < 16; ++i) {
        int e = i * 256 + tid;
        int kk = e >> 6, nn = e & 63;
        Wt[kk][nn] = W[(size_t)(k0 + kk) * D_OUT + n0 + nn];
    }
    #pragma unroll
    for (int i = 0; i < 4; ++i) {
        int e = i * 256 + tid;
        int r = e >> 6, nn = e & 63;
        b0t[nn][r] = b0[(size_t)r * D_OUT + n0 + nn];
        b1t[nn][r] = b1[(size_t)r * D_OUT + n0 + nn];
    }
    const int kk = tid & 63;
    float4 A0[4], A1[4];
    #pragma unroll
    for (int c = 0; c < 4; ++c) {
        A0[c] = *(const float4*)(a0 + (size_t)(k0 + kk) * RANKR + c * 4);
        A1[c] = *(const float4*)(a1 + (size_t)(k0 + kk) * RANKR + c * 4);
    }
    __syncthreads();

    const float s2 = 1.0f / 256.0f;   // (ALPHA/RANK)^2
    #pragma unroll
    for (int i = 0; i < 16; ++i) {
        int nn = i * 4 + (tid >> 6);          // wave-uniform -> broadcast reads
        float d0 = 0.f, d1 = 0.f;
        #pragma unroll
        for (int c = 0; c < 4; ++c) {
            float4 bv0 = *(const float4*)&b0t[nn][c * 4];
            float4 bv1 = *(const float4*)&b1t[nn][c * 4];
            d0 += A0[c].x * bv0.x + A0[c].y * bv0.y + A0[c].z * bv0.z + A0[c].w * bv0.w;
            d1 += A1[c].x * bv1.x + A1[c].y * bv1.y + A1[c].z * bv1.z + A1[c].w * bv1.w;
        }
        float v = Wt[kk][nn] + s2 * d0 * d1;
        Bt[(size_t)(n0 + nn) * D_IN + k0 + kk] = f2bf(v);
    }
}

// ---------------------------------------------------------------------------
// gemm: C[m][n] = sum_k A[m][k]*Bt[n][k] + bias[n]   (bf16 MFMA, fp32 acc)
// 256x256 tile, BK=64 (two 256x32 K-planes), 8 waves 2(M)x4(N), wave 128x64.
// LDS per plane: [256 rows][4 chunks of 16B], chunk swizzled by (row>>1)&3.
// ---------------------------------------------------------------------------
#define BAR do { asm volatile("" ::: "memory");                  \
                 __builtin_amdgcn_s_barrier();                   \
                 asm volatile("" ::: "memory"); } while (0)
#define VMC(N) asm volatile("s_waitcnt vmcnt(" #N ")" ::: "memory")
#define LGKM0  asm volatile("s_waitcnt lgkmcnt(0)" ::: "memory")

#define STG_A(NB, KK, KTN) do {                                               \
    glds16(Ag + gof0 + (KTN) + (KK) * 32, (char*)&As[NB][KK][0] + ldw0);      \
    glds16(Ag + gof1 + (KTN) + (KK) * 32, (char*)&As[NB][KK][0] + ldw1);      \
  } while (0)
#define STG_B(NB, KK, KTN) do {                                               \
    glds16(Bg + gof0 + (KTN) + (KK) * 32, (char*)&Bs[NB][KK][0] + ldw0);      \
    glds16(Bg + gof1 + (KTN) + (KK) * 32, (char*)&Bs[NB][KK][0] + ldw1);      \
  } while (0)

#define RD(DST, SRC, ROWB) _Pragma("unroll")                                  \
    for (int i_ = 0; i_ < 4; ++i_)                                            \
      DST[i_] = *(const short8*)(&SRC[((ROWB) + i_ * 16) * 32 + rc8]);

#define MM(AO, AF, BF) do {                                                   \
    __builtin_amdgcn_s_setprio(1);                                            \
    _Pragma("unroll")                                                         \
    for (int i_ = 0; i_ < 4; ++i_)                                            \
      _Pragma("unroll")                                                       \
      for (int j_ = 0; j_ < 4; ++j_)                                          \
        acc[(AO) + i_][j_] = __builtin_amdgcn_mfma_f32_16x16x32_bf16(         \
            AF[i_], BF[j_], acc[(AO) + i_][j_], 0, 0, 0);                     \
    __builtin_amdgcn_s_setprio(0);                                            \
  } while (0)

// One steady-state K-tile (4 phases). Stages planes of tile T+1 into buf !BUF.
#define TILE(T, BUF) do {                                                     \
    const int ktn_ = ((T) + 1) * 64;                                          \
    /*P0*/ RD(a0k0, As[BUF][0], arow); RD(b0, Bs[BUF][0], brow);              \
           STG_A(!(BUF), 0, ktn_);                                            \
           BAR; LGKM0; MM(4, a1k1, b1); BAR;                                  \
    /*P1*/ RD(a1k0, As[BUF][0], arow + 64);                                   \
           STG_B(!(BUF), 0, ktn_); VMC(4);                                    \
           BAR; LGKM0; MM(0, a0k0, b0); BAR;                                  \
    /*P2*/ RD(a0k1, As[BUF][1], arow); RD(b1, Bs[BUF][1], brow);              \
           STG_A(!(BUF), 1, ktn_);                                            \
           BAR; LGKM0; MM(4, a1k0, b0); BAR;                                  \
    /*P3*/ RD(a1k1, As[BUF][1], arow + 64);                                   \
           STG_B(!(BUF), 1, ktn_); VMC(4);                                    \
           BAR; LGKM0; MM(0, a0k1, b1); BAR;                                  \
  } while (0)

__global__ __launch_bounds__(512, 2) void gemm_bt(
    const unsigned short* __restrict__ A,   // [MROWS][D_IN] bf16
    const unsigned short* __restrict__ B,   // [D_OUT][D_IN] bf16 (transposed)
    const float* __restrict__ bias,
    float* __restrict__ C) {
    __shared__ __align__(16) unsigned short As[2][2][8192];   // 64 KiB
    __shared__ __align__(16) unsigned short Bs[2][2][8192];   // 64 KiB

    const int tid  = threadIdx.x;
    const int wave = tid >> 6, lane = tid & 63;
    const int quad = lane >> 4, l16 = lane & 15;
    // read chunk: key(row)=(row>>1)&3 == (l16>>1)&3 (rows are 16-aligned+l16)
    const int rc8 = (quad ^ ((l16 >> 1) & 3)) * 8;

    // XCD-chunked bijective swizzle (nwg=1024, %8==0)
    const int bid = blockIdx.y * 16 + blockIdx.x;
    const int swz = (bid & 7) * 128 + (bid >> 3);
    const int m0 = (swz >> 4) * 256, n0 = (swz & 15) * 256;
    const int wm = wave >> 2, wn = wave & 3;       // 2x4 wave grid
    const int arow = wm * 128 + l16;               // + mh*64 + i*16
    const int brow = wn * 64 + l16;                // + j*16

    const unsigned short* Ag = A + (size_t)m0 * D_IN;
    const unsigned short* Bg = B + (size_t)n0 * D_IN;

    // staging: e = r*512+tid; row=e>>2, chunk=e&3, global chunk = chunk^key
    const int e0 = tid, e1 = 512 + tid;
    const size_t gof0 = (size_t)(e0 >> 2) * D_IN + (size_t)(((e0 & 3) ^ ((e0 >> 3) & 3)) * 8);
    const size_t gof1 = (size_t)(e1 >> 2) * D_IN + (size_t)(((e1 & 3) ^ ((e1 >> 3) & 3)) * 8);
    const unsigned ldw0 = wave * 1024;             // byte offsets within plane
    const unsigned ldw1 = 8192 + wave * 1024;

    short8 a0k0[4], a1k0[4], a0k1[4], a1k1[4], b0[4], b1[4];
    floatx4 acc[8][4] = {};

    // prologue: stage tile0 (all 4 planes) + tile1 (k0 planes) = 12 loads
    STG_A(0, 0, 0); STG_B(0, 0, 0); STG_A(0, 1, 0); STG_B(0, 1, 0);
    STG_A(1, 0, 64); STG_B(1, 0, 64);
    VMC(8);                 // tile0 k0 planes landed
    BAR;

    // peeled tile 0 (buf 0): no P0 MFMA; tile1 k0 stages were hoisted
    /*P0*/ RD(a0k0, As[0][0], arow); RD(b0, Bs[0][0], brow); BAR;
    /*P1*/ RD(a1k0, As[0][0], arow + 64); VMC(4);            // tile0 k1 landed
           BAR; LGKM0; MM(0, a0k0, b0); BAR;
    /*P2*/ RD(a0k1, As[0][1], arow); RD(b1, Bs[0][1], brow);
           STG_A(1, 1, 64);
           BAR; LGKM0; MM(4, a1k0, b0); BAR;
    /*P3*/ RD(a1k1, As[0][1], arow + 64);
           STG_B(1, 1, 64); VMC(4);                          // tile1 k0 landed
           BAR; LGKM0; MM(0, a0k1, b1); BAR;

    // main loop: tiles 1..62 (odd buf1, even buf0); 64 tiles total
    for (int t = 1; t < NTILES - 2; t += 2) {
        TILE(t, 1);
        TILE(t + 1, 0);
    }

    // peeled tile 63 (buf 1): no stages; drain vmcnt at P1
    /*P0*/ RD(a0k0, As[1][0], arow); RD(b0, Bs[1][0], brow);
           BAR; LGKM0; MM(4, a1k1, b1); BAR;
    /*P1*/ RD(a1k0, As[1][0], arow + 64); VMC(0);
           BAR; LGKM0; MM(0, a0k0, b0); BAR;
    /*P2*/ RD(a0k1, As[1][1], arow); RD(b1, Bs[1][1], brow);
           BAR; LGKM0; MM(4, a1k0, b0); BAR;
    /*P3*/ RD(a1k1, As[1][1], arow + 64);
           BAR; LGKM0; MM(0, a0k1, b1); BAR;
    /*final quadrant*/ MM(4, a1k1, b1);

    // epilogue: C/D layout col=lane&15, row=quad*4+reg; fuse bias; NT stores
    #pragma unroll
    for (int nt = 0; nt < 4; ++nt) {
        int col = n0 + wn * 64 + nt * 16 + l16;
        float bv = bias[col];
        #pragma unroll
        for (int mt = 0; mt < 8; ++mt) {
            int r0 = m0 + wm * 128 + mt * 16 + quad * 4;
            #pragma unroll
            for (int r = 0; r < 4; ++r) {
                float v = acc[mt][nt][r] + bv;
                __builtin_nontemporal_store(v, &C[(size_t)(r0 + r) * D_OUT + col]);
            }
        }
    }
}

extern "C" void kernel_launch(void* const* d_in, const int* in_sizes, int n_in,
                              void* d_out, int out_size, void* d_ws, size_t ws_size,
                              hipStream_t stream) {
    const float* x    = (const float*)d_in[0];
    const float* W    = (const float*)d_in[1];
    const float* bias = (const float*)d_in[2];
    const float* a0   = (const float*)d_in[3];
    const float* b0   = (const float*)d_in[4];
    const float* a1   = (const float*)d_in[5];
    const float* b1   = (const float*)d_in[6];
    float* out = (float*)d_out;

    unsigned short* xb = (unsigned short*)d_ws;                                      // 128 MB
    unsigned short* Bt = (unsigned short*)((char*)d_ws + (size_t)MROWS * D_IN * 2);  // 32 MB

    cvt_x<<<(MROWS * (size_t)D_IN) / 2048, 256, 0, stream>>>(x, xb);
    prep_bt<<<4096, 256, 0, stream>>>(W, a0, b0, a1, b1, Bt);
    gemm_bt<<<dim3(D_OUT / 256, MROWS / 256), 512, 0, stream>>>(xb, Bt, bias, out);
}

// Round 5
// 955.344 us; speedup vs baseline: 1.2111x; 1.0497x over previous
//
#include <hip/hip_runtime.h>

// LoHA: out = x @ (W + (a0@b0/16) * (a1@b1/16)) + bias
// R7 (= R6 with compile fix: NT loads via clang ext_vector type, not
// HIP_vector_type, which __builtin_nontemporal_load rejects):
//     (1) gemm: 2 phases per K-tile (was 4) -> 4 barriers + 2 lgkm + 2 vmcnt
//     per BK=64 tile. Each phase: 12 ds_read_b128 + 4 glds16 + VMC(4) + BAR +
//     LGKM0 + 32 MFMA + BAR. Counted-vmcnt FIFO: entering tile T Ph0 the
//     in-flight set is exactly T's k1 planes; VMC(4)@Ph0 retires them,
//     VMC(4)@Ph1 retires T+1's k0. Swizzles (conflict-free, verified 0 in R5)
//     unchanged. (2) cvt_x + prep_bt merged into one launch (cvt blocks
//     first); NT loads for x/W (single-use) to keep xb/Bt in L3 for the gemm.
// Workspace: xb (bf16, 134217728 B) @ 0; Bt (bf16, 33554432 B) @ 134217728.

#define D_IN   4096
#define D_OUT  4096
#define RANKR  16
#define MROWS  16384
#define NTILES 64    // K tiles of BK=64  (64*64 = 4096 = D_IN)
#define NCVT   32768 // cvt blocks: 32768*2048 = 16384*4096 elems

typedef __attribute__((ext_vector_type(8))) short short8;
typedef __attribute__((ext_vector_type(4))) float floatx4;
typedef __attribute__((ext_vector_type(4))) unsigned int uintx4;

__device__ __forceinline__ unsigned short f2bf(float f) {
    union { float f; unsigned u; } c; c.f = f;
    unsigned r = c.u + 0x7fffu + ((c.u >> 16) & 1u);   // round-to-nearest-even
    return (unsigned short)(r >> 16);
}

__device__ __forceinline__ void glds16(const void* g, void* l) {
    __builtin_amdgcn_global_load_lds(
        (const __attribute__((address_space(1))) void*)g,
        (__attribute__((address_space(3))) void*)l, 16, 0, 0);
}

// ---------------------------------------------------------------------------
// prep: blocks [0,NCVT) convert x fp32->bf16 (8 elem/thread);
//       blocks [NCVT,NCVT+4096) build Bt[n][k].
// ---------------------------------------------------------------------------
__global__ __launch_bounds__(256) void prep(
    const float* __restrict__ W,  const float* __restrict__ a0,
    const float* __restrict__ b0, const float* __restrict__ a1,
    const float* __restrict__ b1, unsigned short* __restrict__ Bt,
    const float* __restrict__ x,  unsigned short* __restrict__ xb) {
    const int tid = threadIdx.x;
    if (blockIdx.x < NCVT) {
        size_t i = ((size_t)blockIdx.x * 256 + tid) * 8;
        const floatx4* p = (const floatx4*)(x + i);
        floatx4 v0 = __builtin_nontemporal_load(p);
        floatx4 v1 = __builtin_nontemporal_load(p + 1);
        union { unsigned short u[8]; uintx4 q; } o;
        o.u[0] = f2bf(v0.x); o.u[1] = f2bf(v0.y);
        o.u[2] = f2bf(v0.z); o.u[3] = f2bf(v0.w);
        o.u[4] = f2bf(v1.x); o.u[5] = f2bf(v1.y);
        o.u[6] = f2bf(v1.z); o.u[7] = f2bf(v1.w);
        *(uintx4*)(xb + i) = o.q;
        return;
    }
    __shared__ float Wt[64][65];
    __shared__ float b0t[64][20], b1t[64][20];   // [nn][r], stride 20
    const int pb = blockIdx.x - NCVT;
    const int k0 = (pb & 63) * 64, n0 = (pb >> 6) * 64;

    #pragma unroll
    for (int i = 0; i < 16; ++i) {
        int e = i * 256 + tid;
        int kk = e >> 6, nn = e & 63;
        Wt[kk][nn] = __builtin_nontemporal_load(
            W + (size_t)(k0 + kk) * D_OUT + n0 + nn);
    }
    #pragma unroll
    for (int i = 0; i < 4; ++i) {
        int e = i * 256 + tid;
        int r = e >> 6, nn = e & 63;
        b0t[nn][r] = b0[(size_t)r * D_OUT + n0 + nn];
        b1t[nn][r] = b1[(size_t)r * D_OUT + n0 + nn];
    }
    const int kk = tid & 63;
    floatx4 A0[4], A1[4];
    #pragma unroll
    for (int c = 0; c < 4; ++c) {
        A0[c] = *(const floatx4*)(a0 + (size_t)(k0 + kk) * RANKR + c * 4);
        A1[c] = *(const floatx4*)(a1 + (size_t)(k0 + kk) * RANKR + c * 4);
    }
    __syncthreads();

    const float s2 = 1.0f / 256.0f;   // (ALPHA/RANK)^2
    #pragma unroll
    for (int i = 0; i < 16; ++i) {
        int nn = i * 4 + (tid >> 6);          // wave-uniform -> broadcast reads
        float d0 = 0.f, d1 = 0.f;
        #pragma unroll
        for (int c = 0; c < 4; ++c) {
            floatx4 bv0 = *(const floatx4*)&b0t[nn][c * 4];
            floatx4 bv1 = *(const floatx4*)&b1t[nn][c * 4];
            d0 += A0[c].x * bv0.x + A0[c].y * bv0.y + A0[c].z * bv0.z + A0[c].w * bv0.w;
            d1 += A1[c].x * bv1.x + A1[c].y * bv1.y + A1[c].z * bv1.z + A1[c].w * bv1.w;
        }
        float v = Wt[kk][nn] + s2 * d0 * d1;
        Bt[(size_t)(n0 + nn) * D_IN + k0 + kk] = f2bf(v);
    }
}

// ---------------------------------------------------------------------------
// gemm: C[m][n] = sum_k A[m][k]*Bt[n][k] + bias[n]   (bf16 MFMA, fp32 acc)
// 256x256 tile, BK=64 (two 256x32 K-planes), 8 waves 2(M)x4(N), wave 128x64.
// LDS per plane: [256 rows][4 chunks of 16B], chunk swizzled by (row>>1)&3.
// 2 phases per K-tile; VMC(4) per phase; no vmcnt(0) in the main loop.
// ---------------------------------------------------------------------------
#define BAR do { asm volatile("" ::: "memory");                  \
                 __builtin_amdgcn_s_barrier();                   \
                 asm volatile("" ::: "memory"); } while (0)
#define VMC(N) asm volatile("s_waitcnt vmcnt(" #N ")" ::: "memory")
#define LGKM0  asm volatile("s_waitcnt lgkmcnt(0)" ::: "memory")

#define STG_A(NB, KK, KTN) do {                                               \
    glds16(Ag + gof0 + (KTN) + (KK) * 32, (char*)&As[NB][KK][0] + ldw0);      \
    glds16(Ag + gof1 + (KTN) + (KK) * 32, (char*)&As[NB][KK][0] + ldw1);      \
  } while (0)
#define STG_B(NB, KK, KTN) do {                                               \
    glds16(Bg + gof0 + (KTN) + (KK) * 32, (char*)&Bs[NB][KK][0] + ldw0);      \
    glds16(Bg + gof1 + (KTN) + (KK) * 32, (char*)&Bs[NB][KK][0] + ldw1);      \
  } while (0)

#define RD(DST, SRC, ROWB) _Pragma("unroll")                                  \
    for (int i_ = 0; i_ < 4; ++i_)                                            \
      DST[i_] = *(const short8*)(&SRC[((ROWB) + i_ * 16) * 32 + rc8]);

#define MM(AO, AF, BF) do {                                                   \
    __builtin_amdgcn_s_setprio(1);                                            \
    _Pragma("unroll")                                                         \
    for (int i_ = 0; i_ < 4; ++i_)                                            \
      _Pragma("unroll")                                                       \
      for (int j_ = 0; j_ < 4; ++j_)                                          \
        acc[(AO) + i_][j_] = __builtin_amdgcn_mfma_f32_16x16x32_bf16(         \
            AF[i_], BF[j_], acc[(AO) + i_][j_], 0, 0, 0);                     \
    __builtin_amdgcn_s_setprio(0);                                            \
  } while (0)

// One K-tile, 2 phases. Stages planes of tile T+1 into buf !BUF.
// Invariant entering Ph0: in-flight = tile T's k1 planes (4 loads).
#define TILE2(T, BUF) do {                                                    \
    const int ktn_ = ((T) + 1) * 64;                                          \
    /*Ph0*/ RD(af0, As[BUF][0], arow); RD(af1, As[BUF][0], arow + 64);        \
            RD(bf0, Bs[BUF][0], brow);                                        \
            STG_A(!(BUF), 0, ktn_); STG_B(!(BUF), 0, ktn_);                   \
            VMC(4); BAR; LGKM0;                                               \
            MM(0, af0, bf0); MM(4, af1, bf0);                                 \
            BAR;                                                              \
    /*Ph1*/ RD(ag0, As[BUF][1], arow); RD(ag1, As[BUF][1], arow + 64);        \
            RD(bf1, Bs[BUF][1], brow);                                        \
            STG_A(!(BUF), 1, ktn_); STG_B(!(BUF), 1, ktn_);                   \
            VMC(4); BAR; LGKM0;                                               \
            MM(0, ag0, bf1); MM(4, ag1, bf1);                                 \
            BAR;                                                              \
  } while (0)

__global__ __launch_bounds__(512, 2) void gemm_bt(
    const unsigned short* __restrict__ A,   // [MROWS][D_IN] bf16
    const unsigned short* __restrict__ B,   // [D_OUT][D_IN] bf16 (transposed)
    const float* __restrict__ bias,
    float* __restrict__ C) {
    __shared__ __align__(16) unsigned short As[2][2][8192];   // 64 KiB
    __shared__ __align__(16) unsigned short Bs[2][2][8192];   // 64 KiB

    const int tid  = threadIdx.x;
    const int wave = tid >> 6, lane = tid & 63;
    const int quad = lane >> 4, l16 = lane & 15;
    // read chunk: key(row)=(row>>1)&3 == (l16>>1)&3 (rows are 16-aligned+l16)
    const int rc8 = (quad ^ ((l16 >> 1) & 3)) * 8;

    // XCD-chunked bijective swizzle (nwg=1024, %8==0)
    const int bid = blockIdx.y * 16 + blockIdx.x;
    const int swz = (bid & 7) * 128 + (bid >> 3);
    const int m0 = (swz >> 4) * 256, n0 = (swz & 15) * 256;
    const int wm = wave >> 2, wn = wave & 3;       // 2x4 wave grid
    const int arow = wm * 128 + l16;               // + mh*64 + i*16
    const int brow = wn * 64 + l16;                // + j*16

    const unsigned short* Ag = A + (size_t)m0 * D_IN;
    const unsigned short* Bg = B + (size_t)n0 * D_IN;

    // staging: e = r*512+tid; row=e>>2, chunk=e&3, global chunk = chunk^key
    const int e0 = tid, e1 = 512 + tid;
    const size_t gof0 = (size_t)(e0 >> 2) * D_IN + (size_t)(((e0 & 3) ^ ((e0 >> 3) & 3)) * 8);
    const size_t gof1 = (size_t)(e1 >> 2) * D_IN + (size_t)(((e1 & 3) ^ ((e1 >> 3) & 3)) * 8);
    const unsigned ldw0 = wave * 1024;             // byte offsets within plane
    const unsigned ldw1 = 8192 + wave * 1024;

    short8 af0[4], af1[4], ag0[4], ag1[4], bf0[4], bf1[4];
    floatx4 acc[8][4] = {};

    // prologue: stage tile0 k0+k1 (8 loads); VMC(4) retires k0 -> invariant
    STG_A(0, 0, 0); STG_B(0, 0, 0);
    STG_A(0, 1, 0); STG_B(0, 1, 0);
    VMC(4);
    BAR;

    // main loop: tiles 0..61 (even buf0, odd buf1), then tile 62
    for (int t = 0; t < NTILES - 2; t += 2) {
        TILE2(t, 0);
        TILE2(t + 1, 1);
    }
    TILE2(NTILES - 2, 0);   // tile 62: stages tile 63 (ktn = 4032)

    // peeled tile 63 (buf 1): no stages; drain at Ph0
    /*Ph0*/ RD(af0, As[1][0], arow); RD(af1, As[1][0], arow + 64);
            RD(bf0, Bs[1][0], brow);
            VMC(0); BAR; LGKM0;
            MM(0, af0, bf0); MM(4, af1, bf0);
            BAR;
    /*Ph1*/ RD(ag0, As[1][1], arow); RD(ag1, As[1][1], arow + 64);
            RD(bf1, Bs[1][1], brow);
            LGKM0;
            MM(0, ag0, bf1); MM(4, ag1, bf1);

    // epilogue: C/D layout col=lane&15, row=quad*4+reg; fuse bias; NT stores
    #pragma unroll
    for (int nt = 0; nt < 4; ++nt) {
        int col = n0 + wn * 64 + nt * 16 + l16;
        float bv = bias[col];
        #pragma unroll
        for (int mt = 0; mt < 8; ++mt) {
            int r0 = m0 + wm * 128 + mt * 16 + quad * 4;
            #pragma unroll
            for (int r = 0; r < 4; ++r) {
                float v = acc[mt][nt][r] + bv;
                __builtin_nontemporal_store(v, &C[(size_t)(r0 + r) * D_OUT + col]);
            }
        }
    }
}

extern "C" void kernel_launch(void* const* d_in, const int* in_sizes, int n_in,
                              void* d_out, int out_size, void* d_ws, size_t ws_size,
                              hipStream_t stream) {
    const float* x    = (const float*)d_in[0];
    const float* W    = (const float*)d_in[1];
    const float* bias = (const float*)d_in[2];
    const float* a0   = (const float*)d_in[3];
    const float* b0   = (const float*)d_in[4];
    const float* a1   = (const float*)d_in[5];
    const float* b1   = (const float*)d_in[6];
    float* out = (float*)d_out;

    unsigned short* xb = (unsigned short*)d_ws;                                      // 128 MB
    unsigned short* Bt = (unsigned short*)((char*)d_ws + (size_t)MROWS * D_IN * 2);  // 32 MB

    prep<<<NCVT + 4096, 256, 0, stream>>>(W, a0, b0, a1, b1, Bt, x, xb);
    gemm_bt<<<dim3(D_OUT / 256, MROWS / 256), 512, 0, stream>>>(xb, Bt, bias, out);
}